// Round 14
// baseline (3389.883 us; speedup 1.0000x reference)
//
#include <hip/hip_runtime.h>
#include <hip/hip_bf16.h>
#include <cstdint>

// RateModel: h_{s+1} = tanh(W_rec h_s + b_rec + W_in x_s); out = W_out h + b_out
// B=32, Nt=2000 (sequential), N=512, N_in=128, N_out=64.
//
// k_scan R14 = R13 (proven: 3247us) + two tuning deltas:
//  - delta1: s_sleep 5 -> 10 (~640cy). R13's first MALL sample landed at
//    ~770cy after step top vs publish-commit at ~450+-400 jitter -> frequent
//    __all misses costing a full RTT-serialized round (~900cy). Longer delay
//    trades +320cy sleep for -900cy retry when the old timing missed.
//  - delta2: divergent retry -- only stale lanes re-issue polls (exec-masked
//    if(!ok)); satisfied lanes keep validated registers. ~8x less retry MALL
//    traffic. Issue->vmcnt(0)->check stays straight-line (R12 regalloc rule).
//  Protocol unchanged (R4/R11/R13-proven): 4B atoms [hi16|lo13|tag3],
//  tag=step&7, sc0 sc1 (MALL, any WG placement), skew<=1 => stale tag differs
//  by 2 mod 8 => never false-validates; Hex memsetAsync(0) per launch.
//  Deterministic, replay-safe.

#define NB   32
#define NT   2000
#define NIN  128
#define NN   512
#define NOUT 64
#define NBNN (NB * NN)
#define PAR  65536            // bytes per parity slot (u32[32][512])

typedef unsigned short u16;
typedef unsigned int   u32;
typedef unsigned long long u64;
typedef __bf16 bf16x8 __attribute__((ext_vector_type(8)));
typedef float  f32x4  __attribute__((ext_vector_type(4)));
typedef u32    u32x4  __attribute__((ext_vector_type(4)));

static __device__ __forceinline__ u16 f2bf(float f) {
  return __builtin_bit_cast(u16, (__bf16)f);   // RNE
}
static __device__ __forceinline__ float bf2f(u16 u) {
  return (float)__builtin_bit_cast(__bf16, u);
}
static __device__ __forceinline__ void split_hl(float f, u16& hi, u16& lo) {
  const u32 u = __float_as_uint(f);
  hi = (u16)(u >> 16);                                   // truncated bf16
  lo = f2bf(f - __uint_as_float(u & 0xffff0000u));       // residual
}
static __device__ __forceinline__ float fast_tanh(float x) {
  const float xc = fminf(fmaxf(x, -12.f), 12.f);
  const float t = __builtin_amdgcn_exp2f(xc * 2.8853900817779268f); // 2*log2(e)
  return (t - 1.f) * __builtin_amdgcn_rcpf(t + 1.f);
}

// device-scope (MALL) 16B ops; vmcnt-only, invisible to compiler's wait model
static __device__ __forceinline__ u32x4 ld_dev16(const void* p) {
  u32x4 r;
  asm volatile("global_load_dwordx4 %0, %1, off sc0 sc1" : "=v"(r) : "v"(p) : "memory");
  return r;
}
static __device__ __forceinline__ void st_dev16(void* p, u32x4 v) {
  asm volatile("global_store_dwordx4 %0, %1, off sc0 sc1" :: "v"(p), "v"(v) : "memory");
}
static __device__ __forceinline__ void ld_u16a(u32& d, const void* p) {
  asm volatile("global_load_ushort %0, %1, off" : "=v"(d) : "v"(p) : "memory");
}
static __device__ __forceinline__ bool tags8(u32x4 a, u32x4 b, u32 want) {
  return ((a.x & 7u) == want) & ((a.y & 7u) == want) &
         ((a.z & 7u) == want) & ((a.w & 7u) == want) &
         ((b.x & 7u) == want) & ((b.y & 7u) == want) &
         ((b.z & 7u) == want) & ((b.w & 7u) == want);
}

// ---------------- prep: bf16 weight tables --------------------------------
__global__ __launch_bounds__(256) void k_prep_in(const float* __restrict__ Win,
                                                 u16* __restrict__ winh) {
  const int e = blockIdx.x * 256 + threadIdx.x;
  if (e < NN * NIN) winh[e] = f2bf(Win[e]);
}
__global__ __launch_bounds__(256) void k_prep_out(const float* __restrict__ Wout,
                                                  u16* __restrict__ wouth) {
  const int e = blockIdx.x * 256 + threadIdx.x;
  if (e < NOUT * NN) wouth[e] = f2bf(Wout[e]);
}

// ---------------- K1 (MFMA): jx[t][b][n] = sum_k x[b][t][k] * Win[n][k] ----
__global__ __launch_bounds__(256) void k_in(const float* __restrict__ x,
                                            const u16* __restrict__ winh,
                                            u16* __restrict__ jx) {
  const int t = blockIdx.x;
  const int tid = threadIdx.x;
  const int wv = tid >> 6, lane = tid & 63;
  __shared__ u16 Xh[NB][136];
  __shared__ u16 Xl[NB][136];
  {
    const int b = tid >> 3, k0 = (tid & 7) * 16;
    const float* xp = x + ((size_t)b * NT + t) * NIN + k0;
    u16 hb[16], lb[16];
#pragma unroll
    for (int j = 0; j < 16; ++j) split_hl(xp[j], hb[j], lb[j]);
    *(uint4*)&Xh[b][k0]     = *(uint4*)&hb[0];
    *(uint4*)&Xh[b][k0 + 8] = *(uint4*)&hb[8];
    *(uint4*)&Xl[b][k0]     = *(uint4*)&lb[0];
    *(uint4*)&Xl[b][k0 + 8] = *(uint4*)&lb[8];
  }
  __syncthreads();

  const int r15 = lane & 15, kg = lane >> 4;
  const int n0 = 128 * wv;
  f32x4 acc[2][8];
#pragma unroll
  for (int mt = 0; mt < 2; ++mt)
#pragma unroll
    for (int nt = 0; nt < 8; ++nt) acc[mt][nt] = (f32x4){0.f, 0.f, 0.f, 0.f};

#pragma unroll
  for (int kt = 0; kt < 4; ++kt) {
    const int ko = 32 * kt + 8 * kg;
    const bf16x8 ah0 = *(const bf16x8*)&Xh[r15][ko];
    const bf16x8 ah1 = *(const bf16x8*)&Xh[16 + r15][ko];
    const bf16x8 al0 = *(const bf16x8*)&Xl[r15][ko];
    const bf16x8 al1 = *(const bf16x8*)&Xl[16 + r15][ko];
#pragma unroll
    for (int nt = 0; nt < 8; ++nt) {
      const int n = n0 + 16 * nt + r15;
      const bf16x8 bh = *(const bf16x8*)(winh + (size_t)n * NIN + ko);
      acc[0][nt] = __builtin_amdgcn_mfma_f32_16x16x32_bf16(ah0, bh, acc[0][nt], 0, 0, 0);
      acc[1][nt] = __builtin_amdgcn_mfma_f32_16x16x32_bf16(ah1, bh, acc[1][nt], 0, 0, 0);
      acc[0][nt] = __builtin_amdgcn_mfma_f32_16x16x32_bf16(al0, bh, acc[0][nt], 0, 0, 0);
      acc[1][nt] = __builtin_amdgcn_mfma_f32_16x16x32_bf16(al1, bh, acc[1][nt], 0, 0, 0);
    }
  }
#pragma unroll
  for (int mt = 0; mt < 2; ++mt)
#pragma unroll
    for (int nt = 0; nt < 8; ++nt) {
      const int n = n0 + 16 * nt + r15;
#pragma unroll
      for (int r = 0; r < 4; ++r) {
        const int b = 16 * mt + 4 * kg + r;
        jx[((size_t)t * NB + b) * NN + n] = f2bf(acc[mt][nt][r]);
      }
    }
}

// ---------------- K2: sequential scan --------------------------------------
__global__ __launch_bounds__(256) void k_scan(const float* __restrict__ Wrec,
                                              const float* __restrict__ brec,
                                              const u16* __restrict__ jx,
                                              u32* Hex,             // [2][NB][NN] 4B atoms
                                              u16* __restrict__ Hh) // [NT][NB][NN]
{
  const int wg = blockIdx.x;
  const int g = wg & 7, i = wg >> 3;
  const int tid = threadIdx.x;
  const int wv = tid >> 6, lane = tid & 63;

  // stride 528 u16 = 264 dw == 8 (mod 32): B-frag ds_read_b128 2-way -> free (m136)
  __shared__ u16 SHhi[2][4][528];
  __shared__ u16 SHlo[2][4][528];
  __shared__ float Pj[2][4][64];

  const int r15 = lane & 15, kg = lane >> 4;
  const int t64 = tid & 63;
  const float brv = brec[64 * i + t64];

  // resident A-frags: row = lane&15, k = 8*kg + j (contig-8)
  const int arow = 64 * i + 16 * wv + r15;
  bf16x8 afrag[16];
#pragma unroll
  for (int kt = 0; kt < 16; ++kt) {
    const float* wp = Wrec + (size_t)arow * NN + 32 * kt + 8 * kg;
    bf16x8 a;
#pragma unroll
    for (int j = 0; j < 8; ++j) a[j] = (__bf16)wp[j];
    afrag[kt] = a;
  }

  const int sc = wv;                 // staged chain (== wave)
  const int cc = r15;                // D col = chain (valid < 4)
  const int rb = 16 * wv + 4 * kg;   // D row base within WG slice
  const int gch = 4 * g + cc;
  const int ro = 64 * i + rb;        // global rows ro..ro+3 (ro%4==0)
  const bool ownrow = ((t64 >> 3) == i);  // polled rows are own WG's rows

  char* HexB_ = (char*)Hex;
  // consumer: rows 8*t64..+7 of chain sc -> 32B contiguous
  const char* cb = HexB_ + ((size_t)(4 * g + sc) * NN + 8 * t64) * 4;
  // producer: rows ro..ro+3 of chain gch -> one 16B line
  char* pb = HexB_ + ((size_t)gch * NN + ro) * 4;

  const char* jp = (const char*)jx + ((size_t)(NB + 4 * g + sc) * NN + 64 * i + t64) * 2;
  u16* hb = Hh + (size_t)gch * NN + ro;

  const float jxv0 = bf2f(jx[(size_t)(4 * g + sc) * NN + 64 * i + t64]);
  u32 jxu = 0;

  for (int s = 0; s < NT; ++s) {
    const int slot = s & 1;
    if (s > 0) {
      // delta1: longer delay so the first MALL sample lands after the full
      // publish-commit jitter window -> first-round hit for ~all producers
      asm volatile("s_sleep 10" :::);
      const char* cbs = cb + (slot ? PAR : 0);
      const u32 want = (u32)s & 7u;
      u32x4 A0 = ld_dev16(cbs);
      u32x4 A1 = ld_dev16(cbs + 16);
      asm volatile("s_waitcnt vmcnt(0)" ::: "memory");  // also drains jx + acks
      __builtin_amdgcn_sched_barrier(0);
      bool ok = ownrow | tags8(A0, A1, want);
      int guard = 1 << 16;                               // anti-hang only
      while (!__all(ok) && --guard) {
        // delta2: divergent retry -- only stale lanes re-issue (exec-masked);
        // satisfied lanes keep their validated A0/A1 registers
        if (!ok) {
          A0 = ld_dev16(cbs);
          A1 = ld_dev16(cbs + 16);
        }
        asm volatile("s_waitcnt vmcnt(0)" ::: "memory");
        __builtin_amdgcn_sched_barrier(0);
        ok = ownrow | tags8(A0, A1, want);
      }
      if (!ownrow) {
        // unpack: atom = [hi16 | lo13 | tag3]; rows ascend A0.x..A1.w
        const u32x4 hw = {(A0.x >> 16) | (A0.y & 0xffff0000u),
                          (A0.z >> 16) | (A0.w & 0xffff0000u),
                          (A1.x >> 16) | (A1.y & 0xffff0000u),
                          (A1.z >> 16) | (A1.w & 0xffff0000u)};
        const u32x4 lw = {(A0.x & 0xfff8u) | ((A0.y & 0xfff8u) << 16),
                          (A0.z & 0xfff8u) | ((A0.w & 0xfff8u) << 16),
                          (A1.x & 0xfff8u) | ((A1.y & 0xfff8u) << 16),
                          (A1.z & 0xfff8u) | ((A1.w & 0xfff8u) << 16)};
        *(u32x4*)&SHhi[slot][sc][8 * t64] = hw;
        *(u32x4*)&SHlo[slot][sc][8 * t64] = lw;
      }
      Pj[slot][sc][t64] = __uint_as_float(jxu << 16) + brv;
    } else {
      Pj[0][sc][t64] = jxv0 + brv;
    }

    // single barrier per step: drains only LDS writes (globals are vmcnt-only)
    asm volatile("s_waitcnt lgkmcnt(0)" ::: "memory");
    __builtin_amdgcn_s_barrier();
    __builtin_amdgcn_sched_barrier(0);

    // 4 independent MFMA chains: hi/lo x K-halves (breaks dependent latency)
    f32x4 ah0 = {0.f, 0.f, 0.f, 0.f}, ah1 = {0.f, 0.f, 0.f, 0.f};
    f32x4 al0 = {0.f, 0.f, 0.f, 0.f}, al1 = {0.f, 0.f, 0.f, 0.f};
    if (s > 0) {
      const int c4 = cc & 3;
#pragma unroll
      for (int kt = 0; kt < 8; ++kt) {
        const int ko  = 32 * kt + 8 * kg;
        const int ko2 = 32 * (kt + 8) + 8 * kg;
        const bf16x8 bh0 = *(const bf16x8*)&SHhi[slot][c4][ko];
        const bf16x8 bh1 = *(const bf16x8*)&SHhi[slot][c4][ko2];
        const bf16x8 bl0 = *(const bf16x8*)&SHlo[slot][c4][ko];
        const bf16x8 bl1 = *(const bf16x8*)&SHlo[slot][c4][ko2];
        ah0 = __builtin_amdgcn_mfma_f32_16x16x32_bf16(afrag[kt],     bh0, ah0, 0, 0, 0);
        ah1 = __builtin_amdgcn_mfma_f32_16x16x32_bf16(afrag[kt + 8], bh1, ah1, 0, 0, 0);
        al0 = __builtin_amdgcn_mfma_f32_16x16x32_bf16(afrag[kt],     bl0, al0, 0, 0, 0);
        al1 = __builtin_amdgcn_mfma_f32_16x16x32_bf16(afrag[kt + 8], bl1, al1, 0, 0, 0);
      }
    }
    const f32x4 acc = (ah0 + ah1) + (al0 + al1);

    // epilogue: publish FIRST, self-stage own rows, then Hh, then jx prefetch
    const int nsl = (s + 1) & 1;
    if (cc < 4) {
      const u32 tg = (u32)(s + 1) & 7u;
      u32 atom[4];
      u16 hp[4], lp[4];
#pragma unroll
      for (int r = 0; r < 4; ++r) {
        const float pre = acc[r] + Pj[slot][cc][rb + r];
        const float h = fast_tanh(pre);
        const u32 uh = __float_as_uint(h);
        lp[r] = (u16)(f2bf(h - __uint_as_float(uh & 0xffff0000u)) & 0xfff8u);
        hp[r] = (u16)(uh >> 16);
        atom[r] = (uh & 0xffff0000u) | (u32)lp[r] | tg;
      }
      st_dev16(pb + (nsl ? PAR : 0), (u32x4){atom[0], atom[1], atom[2], atom[3]});
      // self-stage own rows into next-slot LDS (never polled; same lo13 values)
      uint2 hw2, lw2;
      hw2.x = (u32)hp[0] | ((u32)hp[1] << 16);
      hw2.y = (u32)hp[2] | ((u32)hp[3] << 16);
      lw2.x = (u32)lp[0] | ((u32)lp[1] << 16);
      lw2.y = (u32)lp[2] | ((u32)lp[3] << 16);
      *(uint2*)&SHhi[nsl][cc][ro] = hw2;
      *(uint2*)&SHlo[nsl][cc][ro] = lw2;
      *(uint2*)hb = hw2;
    }
    hb += NBNN;

    // jx prefetch for next step (different address; no poll hazard)
    if (s + 1 < NT) {
      ld_u16a(jxu, jp);
      jp += 2 * NBNN;
    }
  }
}

// ---------------- K3 (MFMA): out[b][t][o] = sum_n Hh[t][b][n]*Wout[o][n] + bout[o]
__global__ __launch_bounds__(256) void k_out(const u16* __restrict__ Hh,
                                             const u16* __restrict__ wouth,
                                             const float* __restrict__ bout,
                                             float* __restrict__ out) {
  const int t = blockIdx.x;
  const int tid = threadIdx.x;
  const int wv = tid >> 6, lane = tid & 63;
  __shared__ u16 Ah[NB][528];
  {
    const int b = tid >> 3, k0 = (tid & 7) * 64;
    const u16* hp = Hh + ((size_t)t * NB + b) * NN + k0;
#pragma unroll
    for (int j = 0; j < 8; ++j)
      *(uint4*)&Ah[b][k0 + 8 * j] = *(const uint4*)(hp + 8 * j);
  }
  __syncthreads();

  const int r15 = lane & 15, kg = lane >> 4;
  const int o = 16 * wv + r15;
  f32x4 acc[2] = {{0.f, 0.f, 0.f, 0.f}, {0.f, 0.f, 0.f, 0.f}};
#pragma unroll
  for (int kt = 0; kt < 16; ++kt) {
    const int ko = 32 * kt + 8 * kg;
    const bf16x8 b0 = *(const bf16x8*)(wouth + (size_t)o * NN + ko);
    const bf16x8 a0 = *(const bf16x8*)&Ah[r15][ko];
    const bf16x8 a1 = *(const bf16x8*)&Ah[16 + r15][ko];
    acc[0] = __builtin_amdgcn_mfma_f32_16x16x32_bf16(a0, b0, acc[0], 0, 0, 0);
    acc[1] = __builtin_amdgcn_mfma_f32_16x16x32_bf16(a1, b0, acc[1], 0, 0, 0);
  }
  const float bo = bout[o];
#pragma unroll
  for (int mt = 0; mt < 2; ++mt)
#pragma unroll
    for (int r = 0; r < 4; ++r) {
      const int b = 16 * mt + 4 * kg + r;
      out[((size_t)b * NT + t) * NOUT + o] = acc[mt][r] + bo;
    }
}

// ---------------- launch ----------------------------------------------------
// ws: [0, 65,536,000)             jx bf16 [NT][NB][NN]  (post-scan: wouth @ +0)
//     [65,536,000, 131,072,000)   Hh bf16 [NT][NB][NN]  (pre-scan: winh @ +0)
//     [131,072,000, 131,203,072)  Hex u32 [2][NB][NN]   (4B self-tagged atoms)
extern "C" void kernel_launch(void* const* d_in, const int* in_sizes, int n_in,
                              void* d_out, int out_size, void* d_ws, size_t ws_size,
                              hipStream_t stream) {
  (void)in_sizes; (void)n_in; (void)out_size;
  const float* x    = (const float*)d_in[0];
  const float* Wrec = (const float*)d_in[1];
  const float* brec = (const float*)d_in[2];
  const float* Win  = (const float*)d_in[3];
  const float* Wout = (const float*)d_in[4];
  const float* bout = (const float*)d_in[5];
  float* out = (float*)d_out;

  if (ws_size < 131203072ULL) return;  // visible failure beacon

  char* ws = (char*)d_ws;
  u16* jx    = (u16*)ws;
  u16* Hh    = (u16*)(ws + 65536000);
  u32* Hex   = (u32*)(ws + 131072000);
  u16* winh  = (u16*)(ws + 65536000);  // overlays Hh (dead until k_scan)
  u16* wouth = (u16*)ws;               // overlays jx (dead after k_scan)

  hipMemsetAsync(Hex, 0, 2 * PAR, stream);   // kill poison/cross-launch tag aliases
  k_prep_in<<<dim3((NN * NIN + 255) / 256), dim3(256), 0, stream>>>(Win, winh);
  k_in<<<dim3(NT), dim3(256), 0, stream>>>(x, winh, jx);
  k_scan<<<dim3(64), dim3(256), 0, stream>>>(Wrec, brec, jx, Hex, Hh);
  k_prep_out<<<dim3((NOUT * NN + 255) / 256), dim3(256), 0, stream>>>(Wout, wouth);
  k_out<<<dim3(NT), dim3(256), 0, stream>>>(Hh, wouth, bout, out);
}